// Round 2
// baseline (5763.498 us; speedup 1.0000x reference)
//
#include <hip/hip_runtime.h>
#include <cstdint>

// ---------------------------------------------------------------------------
// GCN 2-layer forward, fp32, MI355X.
// out = Â ( drop( Â (x W1) + b1 ) ) W2 + b2,  Â = D^-1/2 (A+I) D^-1/2
// Aggregation in 16-dim space both layers (matmul commutes with Â).
// Dropout mask reproduces jax.random.bernoulli(key(42), 0.5, (N,16)) under
// the PARTITIONABLE threefry scheme (JAX >= 0.5 default):
//   counter = uint64 flat index i -> threefry2x32(key=(0,42), (hi=0, lo=i)),
//   bits = o0 ^ o1, keep <=> bits < 2^31  (uniform mantissa trick, u < 0.5).
// Thread 0 self-checks the threefry core against the Random123 KAT; on
// failure output is forced to 0 (absmax signature 0.2988 = "core broken").
// ---------------------------------------------------------------------------

#define TFR(R) { x0 += x1; x1 = (x1 << (R)) | (x1 >> (32 - (R))); x1 ^= x0; }

__device__ __forceinline__ void tf2x32(uint32_t k0, uint32_t k1,
                                       uint32_t c0, uint32_t c1,
                                       uint32_t& o0, uint32_t& o1) {
    const uint32_t kx = k0 ^ k1 ^ 0x1BD11BDAu;
    uint32_t x0 = c0 + k0, x1 = c1 + k1;
    TFR(13) TFR(15) TFR(26) TFR(6)   x0 += k1; x1 += kx + 1u;
    TFR(17) TFR(29) TFR(16) TFR(24)  x0 += kx; x1 += k0 + 2u;
    TFR(13) TFR(15) TFR(26) TFR(6)   x0 += k0; x1 += k1 + 3u;
    TFR(17) TFR(29) TFR(16) TFR(24)  x0 += k1; x1 += kx + 4u;
    TFR(13) TFR(15) TFR(26) TFR(6)   x0 += kx; x1 += k0 + 5u;
    o0 = x0; o1 = x1;
}

// deg init = 1.0 (self-loop); thread 0 also runs the threefry KAT.
__global__ void k_init(float* __restrict__ deg, int N, uint32_t* __restrict__ kat) {
    int n = blockIdx.x * blockDim.x + threadIdx.x;
    if (n < N) deg[n] = 1.0f;
    if (n == 0) {
        uint32_t o0, o1;
        tf2x32(0u, 0u, 0u, 0u, o0, o1);
        *kat = (o0 == 0x6b200159u && o1 == 0x99ba4efeu) ? 1u : 0u;
    }
}

__global__ void k_deg(const int* __restrict__ col, float* __restrict__ deg, int E) {
    int e = blockIdx.x * blockDim.x + threadIdx.x;
    if (e < E) atomicAdd(&deg[col[e]], 1.0f);
}

__global__ void k_dinv(float* __restrict__ deg, int N) {
    int n = blockIdx.x * blockDim.x + threadIdx.x;
    if (n < N) deg[n] = 1.0f / sqrtf(deg[n]);  // deg >= 1 always
}

// xw1 = x @ W1 ([N,512]@[512,16]); h1 init = dinv^2 * xw1 (self-loop term).
__global__ __launch_bounds__(256) void k_mm1(
    const float* __restrict__ x, const float* __restrict__ W1,
    const float* __restrict__ dinv, float* __restrict__ xw1,
    float* __restrict__ h1, int N) {
    int n = blockIdx.x * blockDim.x + threadIdx.x;
    if (n >= N) return;
    float acc[16];
#pragma unroll
    for (int f = 0; f < 16; ++f) acc[f] = 0.0f;
    const float4* xr = reinterpret_cast<const float4*>(x + (size_t)n * 512);
#pragma unroll 4
    for (int j = 0; j < 128; ++j) {
        float4 xv = xr[j];
        const float* w = W1 + j * 64;  // rows 4j..4j+3 of [512][16]
#pragma unroll
        for (int f = 0; f < 16; ++f)
            acc[f] += xv.x * w[f] + xv.y * w[16 + f] + xv.z * w[32 + f] + xv.w * w[48 + f];
    }
    float dv = dinv[n];
    float dv2 = dv * dv;
    float* xo = xw1 + (size_t)n * 16;
    float* ho = h1 + (size_t)n * 16;
#pragma unroll
    for (int f = 0; f < 16; ++f) {
        xo[f] = acc[f];
        ho[f] = dv2 * acc[f];
    }
}

// Edge scatter, 16-dim: dst[col] += dinv[row]*dinv[col]*src[row]
__global__ void k_scatter16(const int* __restrict__ row, const int* __restrict__ col,
                            const float* __restrict__ dinv, const float* __restrict__ src,
                            float* __restrict__ dst, int E) {
    int e = blockIdx.x * blockDim.x + threadIdx.x;
    if (e >= E) return;
    int r = row[e], c = col[e];
    float nrm = dinv[r] * dinv[c];
    const float4* s = reinterpret_cast<const float4*>(src + (size_t)r * 16);
    float* d = dst + (size_t)c * 16;
#pragma unroll
    for (int j = 0; j < 4; ++j) {
        float4 v = s[j];
        atomicAdd(&d[4 * j + 0], nrm * v.x);
        atomicAdd(&d[4 * j + 1], nrm * v.y);
        atomicAdd(&d[4 * j + 2], nrm * v.z);
        atomicAdd(&d[4 * j + 3], nrm * v.w);
    }
}

// hdrop = mask * (h1 + b1) * 2 ; agg2 = dinv^2 * hdrop (self-loop term).
// agg2 may alias h1 (pure elementwise). KAT failure forces zeros.
__global__ void k_finalize(const float* __restrict__ h1, const float* __restrict__ b1,
                           const float* __restrict__ dinv, float* __restrict__ hdrop,
                           float* __restrict__ agg2, int N,
                           const uint32_t* __restrict__ kat) {
    int i = blockIdx.x * blockDim.x + threadIdx.x;
    if (i >= N * 16) return;
    int n = i >> 4;
    int f = i & 15;
    uint32_t o0, o1;
    tf2x32(0u, 42u, 0u, (uint32_t)i, o0, o1);  // counter = (hi=0, lo=i)
    uint32_t bits = o0 ^ o1;                    // partitionable 32-bit fold
    // keep <=> uniform < 0.5 <=> top bit clear
    float hv = (bits & 0x80000000u) ? 0.0f : (h1[i] + b1[f]) * 2.0f;
    if (*kat == 0u) hv = 0.0f;  // diagnostic signature: absmax == 0.2988
    hdrop[i] = hv;
    float dv = dinv[n];
    agg2[i] = dv * dv * hv;
}

// out = agg2 @ W2 + b2  ([N,16]@[16,40])
__global__ __launch_bounds__(256) void k_mm2(
    const float* __restrict__ agg2, const float* __restrict__ W2,
    const float* __restrict__ b2, float* __restrict__ out, int N) {
    int n = blockIdx.x * blockDim.x + threadIdx.x;
    if (n >= N) return;
    float a[16];
    const float4* s = reinterpret_cast<const float4*>(agg2 + (size_t)n * 16);
#pragma unroll
    for (int j = 0; j < 4; ++j) {
        float4 v = s[j];
        a[4 * j + 0] = v.x; a[4 * j + 1] = v.y; a[4 * j + 2] = v.z; a[4 * j + 3] = v.w;
    }
    float acc[40];
#pragma unroll
    for (int f = 0; f < 40; ++f) acc[f] = b2[f];
#pragma unroll
    for (int k = 0; k < 16; ++k) {
        float av = a[k];
        const float* w = W2 + k * 40;
#pragma unroll
        for (int f = 0; f < 40; ++f) acc[f] += av * w[f];
    }
    float* o = out + (size_t)n * 40;
#pragma unroll
    for (int f = 0; f < 40; ++f) o[f] = acc[f];
}

extern "C" void kernel_launch(void* const* d_in, const int* in_sizes, int n_in,
                              void* d_out, int out_size, void* d_ws, size_t ws_size,
                              hipStream_t stream) {
    const float* x  = (const float*)d_in[0];
    const int*   ei = (const int*)d_in[1];
    const float* W1 = (const float*)d_in[2];
    const float* b1 = (const float*)d_in[3];
    const float* W2 = (const float*)d_in[4];
    const float* b2 = (const float*)d_in[5];
    float* out = (float*)d_out;

    const int E = in_sizes[1] / 2;
    const int N = in_sizes[0] / 512;
    const int* row = ei;       // edge_index[0] (sources)
    const int* col = ei + E;   // edge_index[1] (targets)

    // ws (6.8 MB): dinv[N] | hAgg[16N] (h1 then agg2 in-place) | kat flag
    // d_out (40N floats) doubles as scratch bufA[16N]: xw1 then hdrop,
    // both dead before k_mm2 rewrites d_out from agg2 (in ws).
    float* ws   = (float*)d_ws;
    float* dinv = ws;
    float* hAgg = ws + N;
    uint32_t* kat = (uint32_t*)(ws + (size_t)17 * N);
    float* bufA = (float*)d_out;

    dim3 blk(256);
    dim3 gN((N + 255) / 256);
    dim3 gE((E + 255) / 256);
    dim3 gNF((N * 16 + 255) / 256);

    k_init<<<gN, blk, 0, stream>>>(dinv, N, kat);
    k_deg<<<gE, blk, 0, stream>>>(col, dinv, E);
    k_dinv<<<gN, blk, 0, stream>>>(dinv, N);
    k_mm1<<<gN, blk, 0, stream>>>(x, W1, dinv, bufA /*xw1*/, hAgg /*h1*/, N);
    k_scatter16<<<gE, blk, 0, stream>>>(row, col, dinv, bufA, hAgg, E);
    k_finalize<<<gNF, blk, 0, stream>>>(hAgg /*h1*/, b1, dinv, bufA /*hdrop*/,
                                        hAgg /*agg2 in-place*/, N, kat);
    k_scatter16<<<gE, blk, 0, stream>>>(row, col, dinv, bufA, hAgg, E);
    k_mm2<<<gN, blk, 0, stream>>>(hAgg, W2, b2, out, N);
}

// Round 3
// 899.727 us; speedup vs baseline: 6.4058x; 6.4058x over previous
//
#include <hip/hip_runtime.h>
#include <cstdint>

// ---------------------------------------------------------------------------
// GCN 2-layer forward, fp32, MI355X.
// out = Â ( drop( Â (x W1) + b1 ) ) W2 + b2,  Â = D^-1/2 (A+I) D^-1/2
//
// Round-3 structure: scatter-atomics replaced by CSR build (counting sort by
// target col) + gather aggregation. CSR built once per launch, used by both
// layers. Aggregation identity: with y = dinv .* feat,
//   agg[c] = dinv[c] * ( y[c] + sum_{r in in(c)} y[r] )
// covers both the self-loop (dinv^2 feat[c]) and edge terms (dinv_r dinv_c).
//
// Dropout mask = partitionable threefry2x32 (verified round 2):
//   bits[i] = o0^o1 of tf2x32(key=(0,42), (0, i)); keep <=> bits < 2^31.
// ---------------------------------------------------------------------------

#define TFR(R) { x0 += x1; x1 = (x1 << (R)) | (x1 >> (32 - (R))); x1 ^= x0; }

__device__ __forceinline__ void tf2x32(uint32_t k0, uint32_t k1,
                                       uint32_t c0, uint32_t c1,
                                       uint32_t& o0, uint32_t& o1) {
    const uint32_t kx = k0 ^ k1 ^ 0x1BD11BDAu;
    uint32_t x0 = c0 + k0, x1 = c1 + k1;
    TFR(13) TFR(15) TFR(26) TFR(6)   x0 += k1; x1 += kx + 1u;
    TFR(17) TFR(29) TFR(16) TFR(24)  x0 += kx; x1 += k0 + 2u;
    TFR(13) TFR(15) TFR(26) TFR(6)   x0 += k0; x1 += k1 + 3u;
    TFR(17) TFR(29) TFR(16) TFR(24)  x0 += k1; x1 += kx + 4u;
    TFR(13) TFR(15) TFR(26) TFR(6)   x0 += kx; x1 += k0 + 5u;
    o0 = x0; o1 = x1;
}

// zero cnt; thread 0 runs threefry KAT
__global__ void k_zero(uint32_t* __restrict__ cnt, int N, uint32_t* __restrict__ kat) {
    int i = blockIdx.x * blockDim.x + threadIdx.x;
    if (i < N) cnt[i] = 0u;
    if (i == 0) {
        uint32_t o0, o1;
        tf2x32(0u, 0u, 0u, 0u, o0, o1);
        *kat = (o0 == 0x6b200159u && o1 == 0x99ba4efeu) ? 1u : 0u;
    }
}

__global__ void k_count(const int* __restrict__ col, uint32_t* __restrict__ cnt, int E) {
    int e = blockIdx.x * blockDim.x + threadIdx.x;
    if (e < E) atomicAdd(&cnt[col[e]], 1u);
}

// per-256-block exclusive scan of cnt -> rowptr; block totals -> aux
__global__ void k_scan_block(const uint32_t* __restrict__ cnt, uint32_t* __restrict__ rowptr,
                             uint32_t* __restrict__ aux, int N) {
    __shared__ uint32_t s[256];
    int i = blockIdx.x * 256 + threadIdx.x;
    uint32_t v = (i < N) ? cnt[i] : 0u;
    s[threadIdx.x] = v;
    __syncthreads();
    for (int off = 1; off < 256; off <<= 1) {
        uint32_t t = (threadIdx.x >= (uint32_t)off) ? s[threadIdx.x - off] : 0u;
        __syncthreads();
        s[threadIdx.x] += t;
        __syncthreads();
    }
    if (i < N) rowptr[i] = s[threadIdx.x] - v;  // exclusive within block
    if (threadIdx.x == 255) aux[blockIdx.x] = s[255];
}

// single-block exclusive scan of aux[NB] (chunked, carry in LDS)
__global__ void k_scan_aux(uint32_t* __restrict__ aux, int NB) {
    __shared__ uint32_t s[256];
    __shared__ uint32_t carry;
    if (threadIdx.x == 0) carry = 0u;
    __syncthreads();
    for (int base = 0; base < NB; base += 256) {
        int i = base + threadIdx.x;
        uint32_t v = (i < NB) ? aux[i] : 0u;
        s[threadIdx.x] = v;
        __syncthreads();
        for (int off = 1; off < 256; off <<= 1) {
            uint32_t t = (threadIdx.x >= (uint32_t)off) ? s[threadIdx.x - off] : 0u;
            __syncthreads();
            s[threadIdx.x] += t;
            __syncthreads();
        }
        uint32_t excl = s[threadIdx.x] - v + carry;
        if (i < NB) aux[i] = excl;
        __syncthreads();
        if (threadIdx.x == 255) carry += s[255];
        __syncthreads();
    }
}

// rowptr += block offset; head = rowptr; dinv = rsqrt(1 + cnt); rowptr[N] = E
__global__ void k_finish_csr(const uint32_t* __restrict__ cnt, uint32_t* __restrict__ rowptr,
                             const uint32_t* __restrict__ aux, uint32_t* __restrict__ head,
                             float* __restrict__ dinv, int N, int E) {
    int i = blockIdx.x * 256 + threadIdx.x;
    if (i < N) {
        uint32_t rp = rowptr[i] + aux[blockIdx.x];
        rowptr[i] = rp;
        head[i] = rp;
        dinv[i] = rsqrtf(1.0f + (float)cnt[i]);
    }
    if (i == 0) rowptr[N] = (uint32_t)E;
}

__global__ void k_fill(const int* __restrict__ row, const int* __restrict__ col,
                       uint32_t* __restrict__ head, int* __restrict__ esrc, int E) {
    int e = blockIdx.x * blockDim.x + threadIdx.x;
    if (e >= E) return;
    uint32_t pos = atomicAdd(&head[col[e]], 1u);
    esrc[pos] = row[e];
}

// y1 = dinv * (x @ W1)   ([N,512]@[512,16])
__global__ __launch_bounds__(256) void k_mm1(
    const float* __restrict__ x, const float* __restrict__ W1,
    const float* __restrict__ dinv, float* __restrict__ y1, int N) {
    int n = blockIdx.x * blockDim.x + threadIdx.x;
    if (n >= N) return;
    float acc[16];
#pragma unroll
    for (int f = 0; f < 16; ++f) acc[f] = 0.0f;
    const float4* xr = reinterpret_cast<const float4*>(x + (size_t)n * 512);
#pragma unroll 4
    for (int j = 0; j < 128; ++j) {
        float4 xv = xr[j];
        const float* w = W1 + j * 64;
#pragma unroll
        for (int f = 0; f < 16; ++f)
            acc[f] += xv.x * w[f] + xv.y * w[16 + f] + xv.z * w[32 + f] + xv.w * w[48 + f];
    }
    float dv = dinv[n];
    float* yo = y1 + (size_t)n * 16;
#pragma unroll
    for (int f = 0; f < 16; ++f) yo[f] = dv * acc[f];
}

// agg[c] = dinv[c] * ( y[c] + sum_{k in [rowptr[c],rowptr[c+1])} y[esrc[k]] )
// 4 lanes per node; each lane owns one float4 of the 16-dim row.
__global__ __launch_bounds__(256) void k_gather16(
    const uint32_t* __restrict__ rowptr, const int* __restrict__ esrc,
    const float* __restrict__ dinv, const float* __restrict__ y,
    float* __restrict__ agg, int N) {
    int t = blockIdx.x * 256 + threadIdx.x;
    int c = t >> 2;
    int j = t & 3;
    if (c >= N) return;
    uint32_t k0 = rowptr[c], k1 = rowptr[c + 1];
    float4 acc = *reinterpret_cast<const float4*>(y + (size_t)c * 16 + j * 4);  // self
    for (uint32_t k = k0; k < k1; ++k) {
        int r = esrc[k];
        float4 v = *reinterpret_cast<const float4*>(y + (size_t)r * 16 + j * 4);
        acc.x += v.x; acc.y += v.y; acc.z += v.z; acc.w += v.w;
    }
    float dc = dinv[c];
    float4 o = make_float4(dc * acc.x, dc * acc.y, dc * acc.z, dc * acc.w);
    *reinterpret_cast<float4*>(agg + (size_t)c * 16 + j * 4) = o;
}

// y2 = dinv * mask * 2 * (agg1 + b1)
__global__ void k_finalize(const float* __restrict__ agg1, const float* __restrict__ b1,
                           const float* __restrict__ dinv, float* __restrict__ y2,
                           int N, const uint32_t* __restrict__ kat) {
    int i = blockIdx.x * blockDim.x + threadIdx.x;
    if (i >= N * 16) return;
    int n = i >> 4;
    int f = i & 15;
    uint32_t o0, o1;
    tf2x32(0u, 42u, 0u, (uint32_t)i, o0, o1);
    uint32_t bits = o0 ^ o1;
    float hv = (bits & 0x80000000u) ? 0.0f : (agg1[i] + b1[f]) * 2.0f;
    if (*kat == 0u) hv = 0.0f;  // diagnostic: forces absmax == 0.2988
    y2[i] = dinv[n] * hv;
}

// out = agg2 @ W2 + b2  ([N,16]@[16,40])
__global__ __launch_bounds__(256) void k_mm2(
    const float* __restrict__ agg2, const float* __restrict__ W2,
    const float* __restrict__ b2, float* __restrict__ out, int N) {
    int n = blockIdx.x * blockDim.x + threadIdx.x;
    if (n >= N) return;
    float a[16];
    const float4* s = reinterpret_cast<const float4*>(agg2 + (size_t)n * 16);
#pragma unroll
    for (int j = 0; j < 4; ++j) {
        float4 v = s[j];
        a[4 * j + 0] = v.x; a[4 * j + 1] = v.y; a[4 * j + 2] = v.z; a[4 * j + 3] = v.w;
    }
    float acc[40];
#pragma unroll
    for (int f = 0; f < 40; ++f) acc[f] = b2[f];
#pragma unroll
    for (int k = 0; k < 16; ++k) {
        float av = a[k];
        const float* w = W2 + k * 40;
#pragma unroll
        for (int f = 0; f < 40; ++f) acc[f] += av * w[f];
    }
    float* o = out + (size_t)n * 40;
#pragma unroll
    for (int f = 0; f < 40; ++f) o[f] = acc[f];
}

extern "C" void kernel_launch(void* const* d_in, const int* in_sizes, int n_in,
                              void* d_out, int out_size, void* d_ws, size_t ws_size,
                              hipStream_t stream) {
    const float* x  = (const float*)d_in[0];
    const int*   ei = (const int*)d_in[1];
    const float* W1 = (const float*)d_in[2];
    const float* b1 = (const float*)d_in[3];
    const float* W2 = (const float*)d_in[4];
    const float* b2 = (const float*)d_in[5];
    float* out = (float*)d_out;

    const int E = in_sizes[1] / 2;
    const int N = in_sizes[0] / 512;
    const int* row = ei;       // sources
    const int* col = ei + E;   // targets

    const int NB1 = (N + 255) / 256;  // scan blocks

    // ws layout (4B words):
    // cnt[N] | rowptr[N+1] | aux[NB1] | head[N] | dinv[N] | esrc[E] | y1[16N] | aggbuf[16N] | kat
    uint32_t* cnt    = (uint32_t*)d_ws;
    uint32_t* rowptr = cnt + N;
    uint32_t* aux    = rowptr + (N + 1);
    uint32_t* head   = aux + NB1;
    float*    dinv   = (float*)(head + N);
    int*      esrc   = (int*)(dinv + N);
    float*    y1     = (float*)(esrc + E);
    float*    aggbuf = y1 + (size_t)16 * N;
    uint32_t* kat    = (uint32_t*)(aggbuf + (size_t)16 * N);
    float*    bufA   = (float*)d_out;  // y2 scratch (16N <= 40N), dead before k_mm2 writes out

    dim3 blk(256);
    dim3 gN((N + 255) / 256);
    dim3 gE((E + 255) / 256);
    dim3 gNF((N * 16 + 255) / 256);
    dim3 gN4((N * 4 + 255) / 256);

    k_zero<<<gN, blk, 0, stream>>>(cnt, N, kat);
    k_count<<<gE, blk, 0, stream>>>(col, cnt, E);
    k_scan_block<<<NB1, blk, 0, stream>>>(cnt, rowptr, aux, N);
    k_scan_aux<<<1, blk, 0, stream>>>(aux, NB1);
    k_finish_csr<<<NB1, blk, 0, stream>>>(cnt, rowptr, aux, head, dinv, N, E);
    k_fill<<<gE, blk, 0, stream>>>(row, col, head, esrc, E);
    k_mm1<<<gN, blk, 0, stream>>>(x, W1, dinv, y1, N);
    k_gather16<<<gN4, blk, 0, stream>>>(rowptr, esrc, dinv, y1, aggbuf, N);
    k_finalize<<<gNF, blk, 0, stream>>>(aggbuf, b1, dinv, bufA /*y2*/, N, kat);
    k_gather16<<<gN4, blk, 0, stream>>>(rowptr, esrc, dinv, bufA, aggbuf, N);
    k_mm2<<<gN, blk, 0, stream>>>(aggbuf, W2, b2, out, N);
}

// Round 4
// 715.204 us; speedup vs baseline: 8.0585x; 1.2580x over previous
//
#include <hip/hip_runtime.h>
#include <cstdint>

// ---------------------------------------------------------------------------
// GCN 2-layer forward, fp32, MI355X.
// out = Â ( drop( Â (x W1) + b1 ) ) W2 + b2,  Â = D^-1/2 (A+I) D^-1/2
//
// Round-4 structure: adjacency as per-target LINKED LIST (atomicExch head +
// coalesced packed[e] = {src, next} 8B writes) instead of counting-sort CSR.
// Kills the 194 MB of write-allocate traffic the esrc scatter-fill paid.
// Degree (for dinv) recovered by a chain-walk kernel (no atomicAdd pass).
// Aggregation identity: with y = dinv .* feat,
//   agg[c] = dinv[c] * ( y[c] + sum_{r in in(c)} y[r] )
//
// Dropout mask = partitionable threefry2x32 (verified round 2):
//   bits[i] = o0^o1 of tf2x32(key=(0,42), (0, i)); keep <=> bits < 2^31.
// Buffer plan: d_out plays y1, then y2, then final out (each dead by reuse).
// ---------------------------------------------------------------------------

#define TFR(R) { x0 += x1; x1 = (x1 << (R)) | (x1 >> (32 - (R))); x1 ^= x0; }

__device__ __forceinline__ void tf2x32(uint32_t k0, uint32_t k1,
                                       uint32_t c0, uint32_t c1,
                                       uint32_t& o0, uint32_t& o1) {
    const uint32_t kx = k0 ^ k1 ^ 0x1BD11BDAu;
    uint32_t x0 = c0 + k0, x1 = c1 + k1;
    TFR(13) TFR(15) TFR(26) TFR(6)   x0 += k1; x1 += kx + 1u;
    TFR(17) TFR(29) TFR(16) TFR(24)  x0 += kx; x1 += k0 + 2u;
    TFR(13) TFR(15) TFR(26) TFR(6)   x0 += k0; x1 += k1 + 3u;
    TFR(17) TFR(29) TFR(16) TFR(24)  x0 += k1; x1 += kx + 4u;
    TFR(13) TFR(15) TFR(26) TFR(6)   x0 += kx; x1 += k0 + 5u;
    o0 = x0; o1 = x1;
}

#define NIL 0xFFFFFFFFu

// head = NIL; thread 0 runs threefry KAT
__global__ void k_init(uint32_t* __restrict__ head, int N, uint32_t* __restrict__ kat) {
    int i = blockIdx.x * blockDim.x + threadIdx.x;
    if (i < N) head[i] = NIL;
    if (i == 0) {
        uint32_t o0, o1;
        tf2x32(0u, 0u, 0u, 0u, o0, o1);
        *kat = (o0 == 0x6b200159u && o1 == 0x99ba4efeu) ? 1u : 0u;
    }
}

// linked-list build: only coalesced 8B writes + 1 atomicExch per edge
__global__ void k_build(const int* __restrict__ row, const int* __restrict__ col,
                        uint32_t* __restrict__ head, uint2* __restrict__ packed, int E) {
    int e = blockIdx.x * blockDim.x + threadIdx.x;
    if (e >= E) return;
    uint32_t r = (uint32_t)row[e];
    int c = col[e];
    uint32_t old = atomicExch(&head[c], (uint32_t)e);
    packed[e] = make_uint2(r, old);
}

// chain walk -> in-degree -> dinv = rsqrt(1 + deg)
__global__ void k_walk(const uint32_t* __restrict__ head, const uint2* __restrict__ packed,
                       float* __restrict__ dinv, int N) {
    int n = blockIdx.x * blockDim.x + threadIdx.x;
    if (n >= N) return;
    uint32_t e = head[n];
    int cnt = 0;
    while (e != NIL) { cnt++; e = packed[e].y; }
    dinv[n] = rsqrtf(1.0f + (float)cnt);
}

// y1 = dinv * (x @ W1)   ([N,512]@[512,16])
__global__ __launch_bounds__(256) void k_mm1(
    const float* __restrict__ x, const float* __restrict__ W1,
    const float* __restrict__ dinv, float* __restrict__ y1, int N) {
    int n = blockIdx.x * blockDim.x + threadIdx.x;
    if (n >= N) return;
    float acc[16];
#pragma unroll
    for (int f = 0; f < 16; ++f) acc[f] = 0.0f;
    const float4* xr = reinterpret_cast<const float4*>(x + (size_t)n * 512);
#pragma unroll 4
    for (int j = 0; j < 128; ++j) {
        float4 xv = xr[j];
        const float* w = W1 + j * 64;
#pragma unroll
        for (int f = 0; f < 16; ++f)
            acc[f] += xv.x * w[f] + xv.y * w[16 + f] + xv.z * w[32 + f] + xv.w * w[48 + f];
    }
    float dv = dinv[n];
    float* yo = y1 + (size_t)n * 16;
#pragma unroll
    for (int f = 0; f < 16; ++f) yo[f] = dv * acc[f];
}

// agg[c] = dinv[c] * ( y[c] + sum over linked list of y[src] )
// 4 lanes per node; lane j owns float4 j of the 16-dim row.
__global__ __launch_bounds__(256) void k_gather16(
    const uint32_t* __restrict__ head, const uint2* __restrict__ packed,
    const float* __restrict__ dinv, const float* __restrict__ y,
    float* __restrict__ agg, int N) {
    int t = blockIdx.x * 256 + threadIdx.x;
    int c = t >> 2;
    int j = t & 3;
    if (c >= N) return;
    float4 acc = *reinterpret_cast<const float4*>(y + (size_t)c * 16 + j * 4);  // self
    uint32_t e = head[c];
    while (e != NIL) {
        uint2 p = packed[e];
        const float4 v = *reinterpret_cast<const float4*>(y + (size_t)p.x * 16 + j * 4);
        acc.x += v.x; acc.y += v.y; acc.z += v.z; acc.w += v.w;
        e = p.y;
    }
    float dc = dinv[c];
    float4 o = make_float4(dc * acc.x, dc * acc.y, dc * acc.z, dc * acc.w);
    *reinterpret_cast<float4*>(agg + (size_t)c * 16 + j * 4) = o;
}

// y2 = dinv * mask * 2 * (agg1 + b1)
__global__ void k_finalize(const float* __restrict__ agg1, const float* __restrict__ b1,
                           const float* __restrict__ dinv, float* __restrict__ y2,
                           int N, const uint32_t* __restrict__ kat) {
    int i = blockIdx.x * blockDim.x + threadIdx.x;
    if (i >= N * 16) return;
    int n = i >> 4;
    int f = i & 15;
    uint32_t o0, o1;
    tf2x32(0u, 42u, 0u, (uint32_t)i, o0, o1);
    uint32_t bits = o0 ^ o1;
    float hv = (bits & 0x80000000u) ? 0.0f : (agg1[i] + b1[f]) * 2.0f;
    if (*kat == 0u) hv = 0.0f;  // diagnostic: forces absmax == 0.2988
    y2[i] = dinv[n] * hv;
}

// out = agg2 @ W2 + b2  ([N,16]@[16,40])
__global__ __launch_bounds__(256) void k_mm2(
    const float* __restrict__ agg2, const float* __restrict__ W2,
    const float* __restrict__ b2, float* __restrict__ out, int N) {
    int n = blockIdx.x * blockDim.x + threadIdx.x;
    if (n >= N) return;
    float a[16];
    const float4* s = reinterpret_cast<const float4*>(agg2 + (size_t)n * 16);
#pragma unroll
    for (int j = 0; j < 4; ++j) {
        float4 v = s[j];
        a[4 * j + 0] = v.x; a[4 * j + 1] = v.y; a[4 * j + 2] = v.z; a[4 * j + 3] = v.w;
    }
    float acc[40];
#pragma unroll
    for (int f = 0; f < 40; ++f) acc[f] = b2[f];
#pragma unroll
    for (int k = 0; k < 16; ++k) {
        float av = a[k];
        const float* w = W2 + k * 40;
#pragma unroll
        for (int f = 0; f < 40; ++f) acc[f] += av * w[f];
    }
    float* o = out + (size_t)n * 40;
#pragma unroll
    for (int f = 0; f < 40; ++f) o[f] = acc[f];
}

extern "C" void kernel_launch(void* const* d_in, const int* in_sizes, int n_in,
                              void* d_out, int out_size, void* d_ws, size_t ws_size,
                              hipStream_t stream) {
    const float* x  = (const float*)d_in[0];
    const int*   ei = (const int*)d_in[1];
    const float* W1 = (const float*)d_in[2];
    const float* b1 = (const float*)d_in[3];
    const float* W2 = (const float*)d_in[4];
    const float* b2 = (const float*)d_in[5];
    float* out = (float*)d_out;

    const int E = in_sizes[1] / 2;
    const int N = in_sizes[0] / 512;
    const int* row = ei;       // sources
    const int* col = ei + E;   // targets

    // ws (≈33 MB): head[N] | dinv[N] | packed[E] (uint2, 8B-aligned) |
    //              aggbuf[16N] | kat
    uint32_t* head   = (uint32_t*)d_ws;
    float*    dinv   = (float*)(head + N);
    uint2*    packed = (uint2*)(dinv + N);        // N even -> 8B aligned
    float*    aggbuf = (float*)(packed + E);
    uint32_t* kat    = (uint32_t*)(aggbuf + (size_t)16 * N);

    // d_out (40N floats) doubles as y-buffer (16N): y1, then y2; both dead
    // before k_mm2 rewrites d_out from aggbuf.
    float* ybuf = (float*)d_out;

    dim3 blk(256);
    dim3 gN((N + 255) / 256);
    dim3 gE((E + 255) / 256);
    dim3 gNF((N * 16 + 255) / 256);
    dim3 gN4((N * 4 + 255) / 256);

    k_init<<<gN, blk, 0, stream>>>(head, N, kat);
    k_build<<<gE, blk, 0, stream>>>(row, col, head, packed, E);
    k_walk<<<gN, blk, 0, stream>>>(head, packed, dinv, N);
    k_mm1<<<gN, blk, 0, stream>>>(x, W1, dinv, ybuf /*y1*/, N);
    k_gather16<<<gN4, blk, 0, stream>>>(head, packed, dinv, ybuf, aggbuf, N);
    k_finalize<<<gNF, blk, 0, stream>>>(aggbuf, b1, dinv, ybuf /*y2*/, N, kat);
    k_gather16<<<gN4, blk, 0, stream>>>(head, packed, dinv, ybuf, aggbuf, N);
    k_mm2<<<gN, blk, 0, stream>>>(aggbuf, W2, b2, out, N);
}